// Round 4
// baseline (209.497 us; speedup 1.0000x reference)
//
#include <hip/hip_runtime.h>
#include <math.h>

#define N    24
#define D    256
#define BLK  256
#define NB   4            // batches per block = waves per block
#define CTS  28           // costT row stride (floats), 16B-aligned
#define INFV 1e9f

__device__ __forceinline__ int rl_i(int x, int l) {
    return __builtin_amdgcn_readlane(x, l);
}
__device__ __forceinline__ float rl_f(float x, int l) {
    return __uint_as_float((unsigned)__builtin_amdgcn_readlane((int)__float_as_uint(x), l));
}
__device__ __forceinline__ float fmin2(float a, float b) { return a < b ? a : b; }

// float min over lanes 0..31 (32..63 reduced separately); valid in lane 31.
__device__ __forceinline__ float dpp_min32(float x) {
    int t;
    t = __builtin_amdgcn_update_dpp(__float_as_int(x), __float_as_int(x), 0xB1,  0xF, 0xF, false);
    x = fmin2(__int_as_float(t), x);   // quad_perm [1,0,3,2]
    t = __builtin_amdgcn_update_dpp(__float_as_int(x), __float_as_int(x), 0x4E,  0xF, 0xF, false);
    x = fmin2(__int_as_float(t), x);   // quad_perm [2,3,0,1]
    t = __builtin_amdgcn_update_dpp(__float_as_int(x), __float_as_int(x), 0x114, 0xF, 0xF, false);
    x = fmin2(__int_as_float(t), x);   // row_shr:4
    t = __builtin_amdgcn_update_dpp(__float_as_int(x), __float_as_int(x), 0x118, 0xF, 0xF, false);
    x = fmin2(__int_as_float(t), x);   // row_shr:8  -> lane15 = min(0..15)
    t = __builtin_amdgcn_update_dpp(__float_as_int(x), __float_as_int(x), 0x142, 0xF, 0xF, false);
    x = fmin2(__int_as_float(t), x);   // row_bcast:15 -> lane31 = min(0..31)
    return x;
}

// C[s][lane] where lane holds column `lane`'s 24 rows in registers; s is SGPR.
__device__ __forceinline__ float sel24(const float (&cq)[24], int s) {
    switch (s) {
        case 0:  return cq[0];  case 1:  return cq[1];
        case 2:  return cq[2];  case 3:  return cq[3];
        case 4:  return cq[4];  case 5:  return cq[5];
        case 6:  return cq[6];  case 7:  return cq[7];
        case 8:  return cq[8];  case 9:  return cq[9];
        case 10: return cq[10]; case 11: return cq[11];
        case 12: return cq[12]; case 13: return cq[13];
        case 14: return cq[14]; case 15: return cq[15];
        case 16: return cq[16]; case 17: return cq[17];
        case 18: return cq[18]; case 19: return cq[19];
        case 20: return cq[20]; case 21: return cq[21];
        case 22: return cq[22]; default: return cq[23];
    }
}

#define DOT4(a, b) ((a).x*(b).x + (a).y*(b).y + (a).z*(b).z + (a).w*(b).w)
#define LGKM0() __asm__ volatile("s_waitcnt lgkmcnt(0)" ::: "memory")

__global__ __launch_bounds__(BLK, 2) void hungarian_fused(
    const float* __restrict__ slots,
    const float* __restrict__ prev,
    float* __restrict__ out, int B)
{
    __shared__ __align__(16) float costT[NB][N][CTS]; // [wave][col][row]
    __shared__ int winner[NB][N];
    __shared__ int colw[NB][N];

    const int tid  = threadIdx.x;
    const int lane = tid & 63;
    const int wv   = tid >> 6;
    const int bw   = blockIdx.x * NB + wv;
    if (bw >= B) return;

    // ============ Phase A: per-wave cost GEMM straight from global =========
    const int rg = lane >> 3;       // prev rows 3rg..3rg+2
    const int cg = lane & 7;        // cur  rows 3cg..3cg+2
    const float4* pA = (const float4*)(prev  + (size_t)bw * N * D) + rg * 3 * (D / 4);
    const float4* pC = (const float4*)(slots + (size_t)bw * N * D) + cg * 3 * (D / 4);

    float s00=0,s01=0,s02=0,s10=0,s11=0,s12=0,s20=0,s21=0,s22=0;
    float pa0=0,pa1=0,pa2=0,pc0=0,pc1=0,pc2=0;
    #pragma unroll 4
    for (int k = 0; k < 64; ++k) {
        float4 a0 = pA[k], a1 = pA[64+k], a2 = pA[128+k];
        float4 b0 = pC[k], b1 = pC[64+k], b2 = pC[128+k];
        s00 += DOT4(a0,b0); s01 += DOT4(a0,b1); s02 += DOT4(a0,b2);
        s10 += DOT4(a1,b0); s11 += DOT4(a1,b1); s12 += DOT4(a1,b2);
        s20 += DOT4(a2,b0); s21 += DOT4(a2,b1); s22 += DOT4(a2,b2);
        pa0 += DOT4(a0,a0); pa1 += DOT4(a1,a1); pa2 += DOT4(a2,a2);
        pc0 += DOT4(b0,b0); pc1 += DOT4(b1,b1); pc2 += DOT4(b2,b2);
    }
    float ira0 = 1.0f / fmaxf(sqrtf(pa0), 1e-12f);
    float ira1 = 1.0f / fmaxf(sqrtf(pa1), 1e-12f);
    float ira2 = 1.0f / fmaxf(sqrtf(pa2), 1e-12f);
    float irc0 = 1.0f / fmaxf(sqrtf(pc0), 1e-12f);
    float irc1 = 1.0f / fmaxf(sqrtf(pc1), 1e-12f);
    float irc2 = 1.0f / fmaxf(sqrtf(pc2), 1e-12f);

    {
        float* ct = &costT[wv][0][0];
        const int cb = cg * 3, rb = rg * 3;
        ct[(cb+0)*CTS + rb+0] = 1.0f - s00*ira0*irc0;
        ct[(cb+1)*CTS + rb+0] = 1.0f - s01*ira0*irc1;
        ct[(cb+2)*CTS + rb+0] = 1.0f - s02*ira0*irc2;
        ct[(cb+0)*CTS + rb+1] = 1.0f - s10*ira1*irc0;
        ct[(cb+1)*CTS + rb+1] = 1.0f - s11*ira1*irc1;
        ct[(cb+2)*CTS + rb+1] = 1.0f - s12*ira1*irc2;
        ct[(cb+0)*CTS + rb+2] = 1.0f - s20*ira2*irc0;
        ct[(cb+1)*CTS + rb+2] = 1.0f - s21*ira2*irc1;
        ct[(cb+2)*CTS + rb+2] = 1.0f - s22*ira2*irc2;
    }
    LGKM0();

    // ============ Phase B: Hungarian (JV) with LAPJV-style init ============
    const bool isCol = (lane < N);
    const int  jj    = isCol ? lane : 0;
    float cq[24];
    {
        const float4* cp4 = (const float4*)&costT[wv][jj][0];
        #pragma unroll
        for (int r = 0; r < 6; ++r) {
            float4 q = cp4[r];
            cq[r*4+0] = q.x; cq[r*4+1] = q.y; cq[r*4+2] = q.z; cq[r*4+3] = q.w;
        }
    }

    // ---- 1. column reduction: v[j] = min_i C[i][j]; greedy assign ----
    float cm = cq[0]; int ri = 0;
    #pragma unroll
    for (int i = 1; i < N; ++i) { if (cq[i] < cm) { cm = cq[i]; ri = i; } }

    if (isCol) winner[wv][lane] = -1;
    LGKM0();
    if (isCol) winner[wv][ri] = lane;     // race; one column wins row ri
    LGKM0();
    int p = -1;                           // row assigned to col `lane`
    if (isCol && winner[wv][ri] == lane) p = ri;
    const int widx = isCol ? lane : 0;
    unsigned long long mm = __ballot(isCol && winner[wv][widx] >= 0);
    unsigned freeRows = (~(unsigned)mm) & ((1u << N) - 1);

    float uu = 0.0f;                      // lane r: row potential u[r]
    float v  = isCol ? cm : INFV;         // lane j: col potential v[j]
    int  way = -1;                        // lane j: parent col on SAP path

    // ---- 2. augmenting row reduction (bounded; exactness-preserving) ----
    {
        int steps = 0;
        while (freeRows && steps < 40) {
            ++steps;
            int f = (int)__builtin_ctz(freeRows);
            float cif = sel24(cq, f);
            float rc  = isCol ? (cif - v) : INFV;
            float u1  = rl_f(dpp_min32(rc), 31);
            unsigned long long e1 = __ballot(rc == u1);
            int j1 = (int)__builtin_ctzll(e1);
            float rc2 = (lane == j1) ? INFV : rc;
            float u2  = rl_f(dpp_min32(rc2), 31);
            if (lane == f) uu = u2;                        // u[f] = 2nd min
            if (lane == j1 && u1 < u2) v -= (u2 - u1);     // tighten col dual
            int iold = rl_i(p, j1);
            if (lane == j1) p = f;
            freeRows &= ~(1u << f);
            if (iold >= 0) freeRows |= (1u << iold);       // bumped row free
        }
    }

    // ---- 3. shortest augmenting paths for remaining free rows ----
    int guard = 0;
    while (freeRows && guard < 1500) {
        const int f = (int)__builtin_ctz(freeRows);
        freeRows &= freeRows - 1;

        float minv  = INFV;
        bool  used  = false;
        bool  inTree = false;
        int   s_j0 = -1;                  // virtual column
        int   s_i0 = f;
        int   j1   = 0;

        while (guard++ < 1500) {
            inTree = inTree || (lane == s_i0);
            used   = used   || (lane == s_j0);

            float cij = sel24(cq, s_i0);
            float u0  = rl_f(uu, s_i0);
            float cur = cij - u0 - v;
            bool  act = isCol && !used;
            if (act && cur < minv) { minv = cur; way = s_j0; }
            float masked = act ? minv : INFV;

            float delta = rl_f(dpp_min32(masked), 31);     // min = delta
            unsigned long long eq = __ballot(masked == delta);
            int j1s = (int)__builtin_ctzll(eq);            // argmin (first)

            if (inTree) uu += delta;
            if (used) v -= delta;
            else if (act) minv -= delta;

            int i0n = rl_i(p, j1s);
            if (i0n < 0) { j1 = j1s; break; }              // free column
            s_j0 = j1s; s_i0 = i0n;
        }

        // augment back to the virtual column
        int jcur = j1, asteps = 0;
        while (asteps++ < 32) {
            int wj   = rl_i(way, jcur);
            int pnew = (wj < 0) ? f : rl_i(p, wj);
            if (lane == jcur) p = pnew;
            if (wj < 0) break;
            jcur = wj;
        }
    }

    if (isCol) colw[wv][p] = lane;        // col_ind[row p] = col `lane`
    LGKM0();

    // ============ Phase C: gather out[i][:] = slots[col[i]][:] =============
    const float4* sg4 = (const float4*)(slots + (size_t)bw * N * D);
    float4*       og4 = (float4*)(out + (size_t)bw * N * D);
    #pragma unroll
    for (int i = 0; i < N; ++i) {
        int c = colw[wv][i];
        og4[i * 64 + lane] = sg4[c * 64 + lane];
    }
}

extern "C" void kernel_launch(void* const* d_in, const int* in_sizes, int n_in,
                              void* d_out, int out_size, void* d_ws, size_t ws_size,
                              hipStream_t stream) {
    const float* slots = (const float*)d_in[0];
    const float* prev  = (const float*)d_in[1];
    float* out = (float*)d_out;
    int B = in_sizes[0] / (N * D);
    int grid = (B + NB - 1) / NB;
    hungarian_fused<<<grid, BLK, 0, stream>>>(slots, prev, out, B);
}

// Round 5
// 198.439 us; speedup vs baseline: 1.0557x; 1.0557x over previous
//
#include <hip/hip_runtime.h>

#define N    24
#define D    256
#define CS   25           // row-major cost stride (floats): conflict-free
#define INFV 1e9f

__device__ __forceinline__ int rl_i(int x, int l) {
    return __builtin_amdgcn_readlane(x, l);
}
__device__ __forceinline__ float rl_f(float x, int l) {
    return __uint_as_float((unsigned)__builtin_amdgcn_readlane((int)__float_as_uint(x), l));
}
__device__ __forceinline__ float fmin2(float a, float b) { return a < b ? a : b; }

// float min over lanes 0..31 (lanes 32..63 must hold INFV); valid in lane 31.
__device__ __forceinline__ float dpp_min32(float x) {
    int t;
    t = __builtin_amdgcn_update_dpp(__float_as_int(x), __float_as_int(x), 0xB1,  0xF, 0xF, false);
    x = fmin2(__int_as_float(t), x);   // quad_perm [1,0,3,2]
    t = __builtin_amdgcn_update_dpp(__float_as_int(x), __float_as_int(x), 0x4E,  0xF, 0xF, false);
    x = fmin2(__int_as_float(t), x);   // quad_perm [2,3,0,1]
    t = __builtin_amdgcn_update_dpp(__float_as_int(x), __float_as_int(x), 0x114, 0xF, 0xF, false);
    x = fmin2(__int_as_float(t), x);   // row_shr:4
    t = __builtin_amdgcn_update_dpp(__float_as_int(x), __float_as_int(x), 0x118, 0xF, 0xF, false);
    x = fmin2(__int_as_float(t), x);   // row_shr:8  -> lane15 = min(0..15)
    t = __builtin_amdgcn_update_dpp(__float_as_int(x), __float_as_int(x), 0x142, 0xF, 0xF, false);
    x = fmin2(__int_as_float(t), x);   // row_bcast:15 -> lane31 = min(0..31)
    return x;
}

#define DOT4(a, b) ((a).x*(b).x + (a).y*(b).y + (a).z*(b).z + (a).w*(b).w)
#define LGKM0() __asm__ volatile("s_waitcnt lgkmcnt(0)" ::: "memory")

__global__ __launch_bounds__(64) void hungarian_fused(
    const float* __restrict__ slots,
    const float* __restrict__ prev,
    float* __restrict__ out, int B)
{
    __shared__ __align__(16) float cost[N * CS];  // cost[i*CS + j], row-major
    __shared__ int winner[N];
    __shared__ int colw[N];

    const int lane = threadIdx.x;      // BLK = 64 = one wave per block
    const int bw   = blockIdx.x;
    if (bw >= B) return;

    // ============ Phase A: cost GEMM straight from global ==================
    // 8x8 lane grid, 3x3 register tile per lane; lanes sharing rg/cg read
    // identical addresses (HW-coalesced broadcast).
    const int rg = lane >> 3;          // prev rows 3rg..3rg+2
    const int cg = lane & 7;           // cur  rows 3cg..3cg+2
    const float4* pA = (const float4*)(prev  + (size_t)bw * N * D) + rg * 3 * (D / 4);
    const float4* pC = (const float4*)(slots + (size_t)bw * N * D) + cg * 3 * (D / 4);

    float s00=0,s01=0,s02=0,s10=0,s11=0,s12=0,s20=0,s21=0,s22=0;
    float pa0=0,pa1=0,pa2=0,pc0=0,pc1=0,pc2=0;
    #pragma unroll 4
    for (int k = 0; k < 64; ++k) {
        float4 a0 = pA[k], a1 = pA[64+k], a2 = pA[128+k];
        float4 b0 = pC[k], b1 = pC[64+k], b2 = pC[128+k];
        s00 += DOT4(a0,b0); s01 += DOT4(a0,b1); s02 += DOT4(a0,b2);
        s10 += DOT4(a1,b0); s11 += DOT4(a1,b1); s12 += DOT4(a1,b2);
        s20 += DOT4(a2,b0); s21 += DOT4(a2,b1); s22 += DOT4(a2,b2);
        pa0 += DOT4(a0,a0); pa1 += DOT4(a1,a1); pa2 += DOT4(a2,a2);
        pc0 += DOT4(b0,b0); pc1 += DOT4(b1,b1); pc2 += DOT4(b2,b2);
    }
    float ira0 = 1.0f / fmaxf(sqrtf(pa0), 1e-12f);
    float ira1 = 1.0f / fmaxf(sqrtf(pa1), 1e-12f);
    float ira2 = 1.0f / fmaxf(sqrtf(pa2), 1e-12f);
    float irc0 = 1.0f / fmaxf(sqrtf(pc0), 1e-12f);
    float irc1 = 1.0f / fmaxf(sqrtf(pc1), 1e-12f);
    float irc2 = 1.0f / fmaxf(sqrtf(pc2), 1e-12f);

    {   // cost[row=prev i][col=cur j] = 1 - dot * ira_i * irc_j
        const int rb = rg * 3, cb = cg * 3;
        cost[(rb+0)*CS + cb+0] = 1.0f - s00*ira0*irc0;
        cost[(rb+0)*CS + cb+1] = 1.0f - s01*ira0*irc1;
        cost[(rb+0)*CS + cb+2] = 1.0f - s02*ira0*irc2;
        cost[(rb+1)*CS + cb+0] = 1.0f - s10*ira1*irc0;
        cost[(rb+1)*CS + cb+1] = 1.0f - s11*ira1*irc1;
        cost[(rb+1)*CS + cb+2] = 1.0f - s12*ira1*irc2;
        cost[(rb+2)*CS + cb+0] = 1.0f - s20*ira2*irc0;
        cost[(rb+2)*CS + cb+1] = 1.0f - s21*ira2*irc1;
        cost[(rb+2)*CS + cb+2] = 1.0f - s22*ira2*irc2;
    }
    LGKM0();   // single wave: ds_write -> ds_read ordering

    // ============ Phase B: Hungarian (JV SAP), column-reduction warm start =
    const bool isCol = (lane < N);
    const int  jc    = isCol ? lane : 23;   // clamped: lanes >=24 broadcast

    // column reduction: v[j] = min_i C[i][j], argmin row per column
    float cm = INFV; int ri = 0;
    #pragma unroll
    for (int i = 0; i < N; ++i) {
        float c = cost[i * CS + jc];
        if (c < cm) { cm = c; ri = i; }
    }
    if (isCol) winner[lane] = -1;
    LGKM0();
    if (isCol) winner[ri] = lane;          // race resolves to one winner
    LGKM0();
    int p = -1;                            // row assigned to col `lane`
    if (isCol && winner[ri] == lane) p = ri;
    unsigned long long mm = __ballot(isCol && winner[lane] >= 0);
    unsigned freeRows = (~(unsigned)mm) & ((1u << N) - 1);

    float uu = 0.0f;                       // lane r: row potential u[r]
    float v  = isCol ? cm : INFV;          // lane j: col potential v[j]
    int  way = -1;                         // lane j: parent col on SAP path

    while (freeRows) {
        const int f = (int)__builtin_ctz(freeRows);
        freeRows &= freeRows - 1;

        float minv = INFV;
        bool  used = false, inTree = false;
        int   s_j0 = -1, s_i0 = f, j1 = 0;

        #pragma unroll 1
        for (int it = 0; it < 26; ++it) {   // tree adds >=1 col/iter: <=25
            float cij = cost[s_i0 * CS + jc];   // ds_read, conflict-free
            inTree |= (lane == s_i0);
            used   |= (lane == s_j0);
            float u0  = rl_f(uu, s_i0);
            float cur = cij - u0 - v;
            bool  act = isCol && !used;
            if (act && cur < minv) { minv = cur; way = s_j0; }
            float masked = act ? minv : INFV;

            float delta = rl_f(dpp_min32(masked), 31);     // min == delta
            unsigned long long eq = __ballot(masked == delta);
            j1 = (int)__builtin_ctzll(eq);                 // lowest-j argmin

            if (inTree) uu += delta;
            if (used) v -= delta;
            else if (act) minv -= delta;

            int i0n = rl_i(p, j1);
            if (i0n < 0) break;                            // free column
            s_j0 = j1; s_i0 = i0n;
        }

        // augment back to the virtual column
        int jcur = j1;
        #pragma unroll 1
        for (int as = 0; as < 26; ++as) {
            int wj   = rl_i(way, jcur);
            int pnew = (wj < 0) ? f : rl_i(p, wj);
            if (lane == jcur) p = pnew;
            if (wj < 0) break;
            jcur = wj;
        }
    }

    if (isCol) colw[p] = lane;             // col_ind[row p] = col `lane`
    LGKM0();

    // ============ Phase C: gather out[i][:] = slots[col[i]][:] =============
    const float4* sg4 = (const float4*)(slots + (size_t)bw * N * D);
    float4*       og4 = (float4*)(out + (size_t)bw * N * D);
    #pragma unroll
    for (int i = 0; i < N; ++i) {
        int c = colw[i];
        og4[i * 64 + lane] = sg4[c * 64 + lane];
    }
}

extern "C" void kernel_launch(void* const* d_in, const int* in_sizes, int n_in,
                              void* d_out, int out_size, void* d_ws, size_t ws_size,
                              hipStream_t stream) {
    const float* slots = (const float*)d_in[0];
    const float* prev  = (const float*)d_in[1];
    float* out = (float*)d_out;
    int B = in_sizes[0] / (N * D);
    hungarian_fused<<<B, 64, 0, stream>>>(slots, prev, out, B);
}